// Round 8
// baseline (190.391 us; speedup 1.0000x reference)
//
#include <hip/hip_runtime.h>
#include <cstdint>
#include <cstddef>

#define NEGV (-1e30f)
#define IL2f 1.44269504088896340736f
#define LN2f 0.693147180559945309417f

__device__ __forceinline__ float exp2_hw(float x) { return __builtin_amdgcn_exp2f(x); }
__device__ __forceinline__ float log2_hw(float x) { return __builtin_amdgcn_logf(x); }

constexpr int Nn = 64, Cc = 64, Tt = 4000, Ss = 100;

// Full-wave lane shifts via DPP; bound_ctrl=true => shifted-in lanes read 0.
__device__ __forceinline__ float wave_shr1(float x) {  // lane n <- lane n-1
    return __int_as_float(__builtin_amdgcn_update_dpp(0, __float_as_int(x), 0x138, 0xF, 0xF, true));
}
__device__ __forceinline__ float wave_shl1(float x) {  // lane n <- lane n+1
    return __int_as_float(__builtin_amdgcn_update_dpp(0, __float_as_int(x), 0x130, 0xF, 0xF, true));
}
__device__ __forceinline__ int wave_shr1_i(int x) {
    return __builtin_amdgcn_update_dpp(0, x, 0x138, 0xF, 0xF, true);
}
__device__ __forceinline__ int wave_shl1_i(int x) {
    return __builtin_amdgcn_update_dpp(0, x, 0x130, 0xF, 0xF, true);
}

typedef float f4 __attribute__((ext_vector_type(4)));
#define LD4(p) (*(const f4*)(p))

// -------- Kernel 1: fused per-(n,t) log2-softmax denominator + probabilities --------
__global__ __launch_bounds__(256) void ctc_softmax_kernel(
    const float* __restrict__ logits, float* __restrict__ d2, float* __restrict__ P)
{
    const int t4 = (blockIdx.x * 256 + threadIdx.x) * 4;
    const int n = blockIdx.y;
    if (t4 >= Tt) return;
    const float* __restrict__ p = logits + (size_t)n * Cc * Tt + t4;
    f4 m, s;
    {
        f4 v = LD4(p);
        #pragma unroll
        for (int i = 0; i < 4; ++i) { m[i] = v[i] * IL2f; s[i] = 1.f; }
    }
    #pragma unroll 4
    for (int c = 1; c < Cc; ++c) {
        f4 v = LD4(p + (size_t)c * Tt);
        #pragma unroll
        for (int i = 0; i < 4; ++i) {
            float vi = v[i] * IL2f;
            float nm = fmaxf(m[i], vi);
            s[i] = s[i] * exp2_hw(m[i] - nm) + exp2_hw(vi - nm);
            m[i] = nm;
        }
    }
    f4 d;
    #pragma unroll
    for (int i = 0; i < 4; ++i) d[i] = m[i] + log2_hw(s[i]);
    *(f4*)(d2 + (size_t)n * Tt + t4) = d;
    if (P) {
        float* __restrict__ dst = P + (size_t)n * Cc * Tt + t4;
        #pragma unroll 4
        for (int c = 0; c < Cc; ++c) {
            f4 v = LD4(p + (size_t)c * Tt);
            f4 o;
            #pragma unroll
            for (int i = 0; i < 4; ++i) o[i] = exp2_hw(fmaf(v[i], IL2f, -d[i]));
            *(f4*)(dst + (size_t)c * Tt) = o;
        }
    }
}

// ---------------- Kernel 2: fwd/bwd recurrence, linear domain, per-lane exponent ----
// 16-step groups, 3-slot register ring, lead-2 prefetch. __launch_bounds__(64,1)
// grants the full VGPR budget (1 wave/EU); each ISSUE is pinned with a volatile
// asm use so the loads cannot be sunk into the consuming body (R7: compiler
// sank them at VGPR=64, destroying the pipeline).
template<bool PRE>
__global__ __launch_bounds__(64, 1) void ctc_fb_kernel(
    const float* __restrict__ PR, const int* __restrict__ targets,
    const int* __restrict__ tlen, const int* __restrict__ ilen,
    const float* __restrict__ d2, float* __restrict__ wsA, float* __restrict__ wsB)
{
    const int bid = blockIdx.x;
    const int n = bid >> 1;
    const bool bwd = bid & 1;
    const int lane = threadIdx.x;
    const int tl = tlen[n];
    const int Tn = ilen[n];
    const int L = 2 * tl + 1;
    const int mid = Tn >> 1;
    const int s0 = 4 * lane;

    const int j1 = min(2 * lane, Ss - 1);
    const int j3 = min(2 * lane + 1, Ss - 1);
    const int base = n * Ss;
    const int tg1 = targets[base + j1];
    const int tg3 = targets[base + j3];
    const int tg1m = targets[base + max(2 * lane - 1, 0)];
    const int tg3p = targets[base + min(2 * lane + 2, Ss - 1)];

    const float sk1f = ((s0 + 1 >= 3) && (tg1 != tg1m)) ? 1.f : 0.f;
    const float sk3f = (tg3 != tg1) ? 1.f : 0.f;
    const float sk1b = ((s0 + 3 < L) && (tg3 != tg1)) ? 1.f : 0.f;
    const float sk3b = ((s0 + 5 < L) && (tg3p != tg3)) ? 1.f : 0.f;

    const float* __restrict__ rB = PR + (size_t)(n * Cc) * Tt;
    const float* __restrict__ r1 = PR + (size_t)(n * Cc + tg1) * Tt;
    const float* __restrict__ r3 = PR + (size_t)(n * Cc + tg3) * Tt;
    const float* __restrict__ rD = d2 + (size_t)n * Tt;

    float a0, a1, a2, a3;
    int E = 0;

    if (!bwd) {
        float pB0, p10;
        if constexpr (PRE) { pB0 = rB[0]; p10 = r1[0]; }
        else {
            const float dv = rD[0];
            pB0 = exp2_hw(fmaf(rB[0], IL2f, -dv));
            p10 = exp2_hw(fmaf(r1[0], IL2f, -dv));
        }
        a0 = (lane == 0) ? pB0 : 0.f;
        a1 = (lane == 0) ? p10 : 0.f;
        a2 = 0.f; a3 = 0.f;
    } else {
        const int te = Tn - 1;
        float pBe, p1e, p3e;
        if constexpr (PRE) { pBe = rB[te]; p1e = r1[te]; p3e = r3[te]; }
        else {
            const float dv = rD[te];
            pBe = exp2_hw(fmaf(rB[te], IL2f, -dv));
            p1e = exp2_hw(fmaf(r1[te], IL2f, -dv));
            p3e = exp2_hw(fmaf(r3[te], IL2f, -dv));
        }
        const int sl = 2 * tl;
        a0 = (s0 == sl) ? pBe : 0.f;
        a1 = (s0 + 1 == sl - 1) ? p1e : 0.f;
        a2 = (s0 + 2 == sl) ? pBe : 0.f;
        a3 = (s0 + 3 == sl - 1) ? p3e : 0.f;
    }

    f4 bB[3][4], bU[3][4], bW[3][4], bD[3][4];

    #define GETP(arr, sl, k) (arr[sl][(k) >> 2][(k) & 3])

    // Pin loaded slot registers: defs must dominate this point; volatile asms are
    // mutually ordered, so loads can't sink into the consuming body.
    #define PIN(sl) {                                                               \
        asm volatile("" : "+v"(bB[sl][0]), "+v"(bB[sl][1]),                         \
                          "+v"(bB[sl][2]), "+v"(bB[sl][3]),                         \
                          "+v"(bU[sl][0]), "+v"(bU[sl][1]),                         \
                          "+v"(bU[sl][2]), "+v"(bU[sl][3]),                         \
                          "+v"(bW[sl][0]), "+v"(bW[sl][1]),                         \
                          "+v"(bW[sl][2]), "+v"(bW[sl][3]));                        \
        if constexpr (!PRE)                                                         \
            asm volatile("" : "+v"(bD[sl][0]), "+v"(bD[sl][1]),                     \
                              "+v"(bD[sl][2]), "+v"(bD[sl][3]));                    \
    }

    if (!bwd) {
        const int tB = mid;                      // steps t = 1..tB
        const int gHi = tB >> 4;                 // 16-step groups

        #define ISSUE_F(gg, sl) {                                                   \
            const int gc_ = min((gg), gHi); const int bo_ = gc_ * 16;               \
            bB[sl][0]=LD4(rB+bo_); bB[sl][1]=LD4(rB+bo_+4);                         \
            bB[sl][2]=LD4(rB+bo_+8); bB[sl][3]=LD4(rB+bo_+12);                      \
            bU[sl][0]=LD4(r1+bo_); bU[sl][1]=LD4(r1+bo_+4);                         \
            bU[sl][2]=LD4(r1+bo_+8); bU[sl][3]=LD4(r1+bo_+12);                      \
            bW[sl][0]=LD4(r3+bo_); bW[sl][1]=LD4(r3+bo_+4);                         \
            bW[sl][2]=LD4(r3+bo_+8); bW[sl][3]=LD4(r3+bo_+12);                      \
            if constexpr (!PRE) {                                                   \
                bD[sl][0]=LD4(rD+bo_); bD[sl][1]=LD4(rD+bo_+4);                     \
                bD[sl][2]=LD4(rD+bo_+8); bD[sl][3]=LD4(rD+bo_+12); }               \
            PIN(sl);                                                                \
        }

        #define BODY_F(gg, us, is) {                                                \
            ISSUE_F((gg) + 2, is);                                                  \
            _Pragma("unroll")                                                       \
            for (int w = 0; w < 2; ++w) {                                           \
                const int Eu = wave_shr1_i(E);                                      \
                const int eb = min(max(127 + (Eu - E), 0), 230);                    \
                const float sc = __int_as_float((unsigned)eb << 23);                \
                const float sk1fs = sk1f * sc;                                      \
                _Pragma("unroll")                                                   \
                for (int kk = 0; kk < 8; ++kk) {                                    \
                    const int k = w * 8 + kk;                                       \
                    const int t = (gg) * 16 + k;                                    \
                    if (t >= 1 && t <= tB) {                                        \
                        float pB, p1, p3;                                           \
                        if constexpr (PRE) {                                        \
                            pB = GETP(bB, us, k); p1 = GETP(bU, us, k);             \
                            p3 = GETP(bW, us, k);                                   \
                        } else {                                                    \
                            const float dv = GETP(bD, us, k);                       \
                            pB = exp2_hw(fmaf(GETP(bB, us, k), IL2f, -dv));         \
                            p1 = exp2_hw(fmaf(GETP(bU, us, k), IL2f, -dv));         \
                            p3 = exp2_hw(fmaf(GETP(bW, us, k), IL2f, -dv));         \
                        }                                                           \
                        const float u3 = wave_shr1(a3);                             \
                        const float n3 = fmaf(a1, sk3f, a3 + a2) * p3;              \
                        const float n2 = (a2 + a1) * pB;                            \
                        const float n1 = fmaf(u3, sk1fs, a1 + a0) * p1;             \
                        const float n0 = fmaf(u3, sc, a0) * pB;                     \
                        a0 = n0; a1 = n1; a2 = n2; a3 = n3;                         \
                    }                                                               \
                }                                                                   \
                const float mx = fmaxf(fmaxf(a0, a1), fmaxf(a2, a3));               \
                const int me = (int)(__float_as_uint(mx) >> 23);                    \
                const float sc2 = __int_as_float((unsigned)(254 - me) << 23);       \
                a0 *= sc2; a1 *= sc2; a2 *= sc2; a3 *= sc2;                         \
                E = (mx > 0.f) ? (E + me - 127) : Eu;                               \
            }                                                                       \
        }

        ISSUE_F(0, 0);
        ISSUE_F(1, 1);
        for (int g = 0; g <= gHi; g += 3) {
            BODY_F(g, 0, 2);
            if (g + 1 <= gHi) BODY_F(g + 1, 1, 0);
            if (g + 2 <= gHi) BODY_F(g + 2, 2, 1);
        }
        #undef BODY_F
        #undef ISSUE_F
    } else {
        const int tB = Tn - 2, tA = mid + 1;     // steps t = tB .. tA (descending)
        const int gHi = tB >> 4, gLo = tA >> 4;

        #define ISSUE_B(gg, sl) {                                                   \
            const int gc_ = max((gg), 0); const int bo_ = gc_ * 16;                 \
            bB[sl][0]=LD4(rB+bo_); bB[sl][1]=LD4(rB+bo_+4);                         \
            bB[sl][2]=LD4(rB+bo_+8); bB[sl][3]=LD4(rB+bo_+12);                      \
            bU[sl][0]=LD4(r1+bo_); bU[sl][1]=LD4(r1+bo_+4);                         \
            bU[sl][2]=LD4(r1+bo_+8); bU[sl][3]=LD4(r1+bo_+12);                      \
            bW[sl][0]=LD4(r3+bo_); bW[sl][1]=LD4(r3+bo_+4);                         \
            bW[sl][2]=LD4(r3+bo_+8); bW[sl][3]=LD4(r3+bo_+12);                      \
            if constexpr (!PRE) {                                                   \
                bD[sl][0]=LD4(rD+bo_); bD[sl][1]=LD4(rD+bo_+4);                     \
                bD[sl][2]=LD4(rD+bo_+8); bD[sl][3]=LD4(rD+bo_+12); }               \
            PIN(sl);                                                                \
        }

        #define BODY_B(gg, us, is) {                                                \
            ISSUE_B((gg) - 2, is);                                                  \
            _Pragma("unroll")                                                       \
            for (int w = 1; w >= 0; --w) {                                          \
                const int Ed = wave_shl1_i(E);                                      \
                const int eb = min(max(127 + (Ed - E), 0), 230);                    \
                const float sc = __int_as_float((unsigned)eb << 23);                \
                const float sk3bs = sk3b * sc;                                      \
                _Pragma("unroll")                                                   \
                for (int kk = 7; kk >= 0; --kk) {                                   \
                    const int k = w * 8 + kk;                                       \
                    const int t = (gg) * 16 + k;                                    \
                    if (t >= tA && t <= tB) {                                       \
                        float pB, p1, p3;                                           \
                        if constexpr (PRE) {                                        \
                            pB = GETP(bB, us, k); p1 = GETP(bU, us, k);             \
                            p3 = GETP(bW, us, k);                                   \
                        } else {                                                    \
                            const float dv = GETP(bD, us, k);                       \
                            pB = exp2_hw(fmaf(GETP(bB, us, k), IL2f, -dv));         \
                            p1 = exp2_hw(fmaf(GETP(bU, us, k), IL2f, -dv));         \
                            p3 = exp2_hw(fmaf(GETP(bW, us, k), IL2f, -dv));         \
                        }                                                           \
                        const float d0 = wave_shl1(a0);                             \
                        const float d1 = wave_shl1(a1);                             \
                        const float n0 = (a0 + a1) * pB;                            \
                        const float n1 = fmaf(a3, sk1b, a1 + a2) * p1;              \
                        const float n2 = (a2 + a3) * pB;                            \
                        const float n3 = fmaf(d1, sk3bs, fmaf(d0, sc, a3)) * p3;    \
                        a0 = n0; a1 = n1; a2 = n2; a3 = n3;                         \
                    }                                                               \
                }                                                                   \
                const float mx = fmaxf(fmaxf(a0, a1), fmaxf(a2, a3));               \
                const int me = (int)(__float_as_uint(mx) >> 23);                    \
                const float sc2 = __int_as_float((unsigned)(254 - me) << 23);       \
                a0 *= sc2; a1 *= sc2; a2 *= sc2; a3 *= sc2;                         \
                E = (mx > 0.f) ? (E + me - 127) : Ed;                               \
            }                                                                       \
        }

        ISSUE_B(gHi, 0);
        ISSUE_B(gHi - 1, 1);
        for (int g = gHi; g >= gLo; g -= 3) {
            BODY_B(g, 0, 2);
            if (g - 1 >= gLo) BODY_B(g - 1, 1, 0);
            if (g - 2 >= gLo) BODY_B(g - 2, 2, 1);
        }
        #undef BODY_B
        #undef ISSUE_B
    }
    #undef PIN
    #undef GETP

    // convert to log2 domain for the combine kernel
    float* dst = (bwd ? wsB : wsA) + n * 256;
    const float Ef = (float)E;
    f4 o;
    o[0] = (s0     < L && a0 > 0.f) ? log2_hw(a0) + Ef : NEGV;
    o[1] = (s0 + 1 < L && a1 > 0.f) ? log2_hw(a1) + Ef : NEGV;
    o[2] = (s0 + 2 < L && a2 > 0.f) ? log2_hw(a2) + Ef : NEGV;
    o[3] = (s0 + 3 < L && a3 > 0.f) ? log2_hw(a3) + Ef : NEGV;
    *(f4*)(dst + s0) = o;
}

// ---------------- Kernel 3: splice alpha*beta, lse over states, mean ----------------
__global__ __launch_bounds__(64) void ctc_combine_kernel(
    const float* __restrict__ wsA, const float* __restrict__ wsB,
    const int* __restrict__ targets, const int* __restrict__ tlen,
    float* __restrict__ out)
{
    const int n = blockIdx.x;
    const int lane = threadIdx.x;
    const int tl = tlen[n];
    const int L = 2 * tl + 1;
    float vals[4];
    float vmax = NEGV;
    #pragma unroll
    for (int k = 0; k < 4; ++k) {
        const int s = lane + (k << 6);
        float v = NEGV;
        if (s < L) {
            const float al = wsA[n * 256 + s];
            const float b0 = wsB[n * 256 + s];
            const float b1 = (s + 1 < L) ? wsB[n * 256 + s + 1] : NEGV;
            const bool skip = (s & 1) && (s + 2 < L) &&
                (targets[n * Ss + (s >> 1) + 1] != targets[n * Ss + (s >> 1)]);
            const float b2 = skip ? wsB[n * 256 + s + 2] : NEGV;
            const float m3 = fmaxf(fmaxf(b0, b1), b2);
            const float B = m3 + log2_hw(exp2_hw(b0 - m3) + exp2_hw(b1 - m3) + exp2_hw(b2 - m3));
            v = al + B;
        }
        vals[k] = v;
        vmax = fmaxf(vmax, v);
    }
    #pragma unroll
    for (int o = 32; o; o >>= 1) vmax = fmaxf(vmax, __shfl_xor(vmax, o));
    float ssum = 0.f;
    #pragma unroll
    for (int k = 0; k < 4; ++k) ssum += exp2_hw(vals[k] - vmax);
    #pragma unroll
    for (int o = 32; o; o >>= 1) ssum += __shfl_xor(ssum, o);
    if (lane == 0) {
        const float total2 = vmax + log2_hw(ssum);
        const float loss = -LN2f * total2;
        atomicAdd(out, loss / ((float)tl * (float)Nn));
    }
}

extern "C" void kernel_launch(void* const* d_in, const int* in_sizes, int n_in,
                              void* d_out, int out_size, void* d_ws, size_t ws_size,
                              hipStream_t stream) {
    const float* logits = (const float*)d_in[0];
    const int* targets  = (const int*)d_in[1];
    const int* tlen     = (const int*)d_in[2];
    const int* ilen     = (const int*)d_in[3];
    float* out = (float*)d_out;

    float* wsA = (float*)d_ws;                     // 64*256
    float* wsB = wsA + Nn * 256;                   // 64*256
    float* d2  = wsB + Nn * 256;                   // 64*4000
    float* P   = d2 + (size_t)Nn * Tt;             // 64*64*4000 (if it fits)
    const size_t need = ((size_t)Nn * 256 * 2 + (size_t)Nn * Tt
                         + (size_t)Nn * Cc * Tt) * sizeof(float);
    const bool pre = (ws_size >= need);

    hipMemsetAsync(d_out, 0, sizeof(float), stream);
    ctc_softmax_kernel<<<dim3(4, Nn), 256, 0, stream>>>(logits, d2, pre ? P : nullptr);
    if (pre) {
        ctc_fb_kernel<true><<<Nn * 2, 64, 0, stream>>>(P, targets, tlen, ilen, d2, wsA, wsB);
    } else {
        ctc_fb_kernel<false><<<Nn * 2, 64, 0, stream>>>(logits, targets, tlen, ilen, d2, wsA, wsB);
    }
    ctc_combine_kernel<<<Nn, 64, 0, stream>>>(wsA, wsB, targets, tlen, out);
}

// Round 9
// 166.475 us; speedup vs baseline: 1.1437x; 1.1437x over previous
//
#include <hip/hip_runtime.h>
#include <cstdint>
#include <cstddef>

#define NEGV (-1e30f)
#define IL2f 1.44269504088896340736f
#define LN2f 0.693147180559945309417f

__device__ __forceinline__ float exp2_hw(float x) { return __builtin_amdgcn_exp2f(x); }
__device__ __forceinline__ float log2_hw(float x) { return __builtin_amdgcn_logf(x); }

constexpr int Nn = 64, Cc = 64, Tt = 4000, Ss = 100;

// Full-wave lane shifts via DPP; bound_ctrl=true => shifted-in lanes read 0.
__device__ __forceinline__ float wave_shr1(float x) {  // lane n <- lane n-1
    return __int_as_float(__builtin_amdgcn_update_dpp(0, __float_as_int(x), 0x138, 0xF, 0xF, true));
}
__device__ __forceinline__ float wave_shl1(float x) {  // lane n <- lane n+1
    return __int_as_float(__builtin_amdgcn_update_dpp(0, __float_as_int(x), 0x130, 0xF, 0xF, true));
}
__device__ __forceinline__ int wave_shr1_i(int x) {
    return __builtin_amdgcn_update_dpp(0, x, 0x138, 0xF, 0xF, true);
}
__device__ __forceinline__ int wave_shl1_i(int x) {
    return __builtin_amdgcn_update_dpp(0, x, 0x130, 0xF, 0xF, true);
}

typedef float f4 __attribute__((ext_vector_type(4)));
#define LD4(p) (*(const f4*)(p))

// -------- Kernel 1: fused per-(n,t) log2-softmax denominator + probabilities --------
__global__ __launch_bounds__(256) void ctc_softmax_kernel(
    const float* __restrict__ logits, float* __restrict__ d2, float* __restrict__ P)
{
    const int t4 = (blockIdx.x * 256 + threadIdx.x) * 4;
    const int n = blockIdx.y;
    if (t4 >= Tt) return;
    const float* __restrict__ p = logits + (size_t)n * Cc * Tt + t4;
    f4 m, s;
    {
        f4 v = LD4(p);
        #pragma unroll
        for (int i = 0; i < 4; ++i) { m[i] = v[i] * IL2f; s[i] = 1.f; }
    }
    #pragma unroll 4
    for (int c = 1; c < Cc; ++c) {
        f4 v = LD4(p + (size_t)c * Tt);
        #pragma unroll
        for (int i = 0; i < 4; ++i) {
            float vi = v[i] * IL2f;
            float nm = fmaxf(m[i], vi);
            s[i] = s[i] * exp2_hw(m[i] - nm) + exp2_hw(vi - nm);
            m[i] = nm;
        }
    }
    f4 d;
    #pragma unroll
    for (int i = 0; i < 4; ++i) d[i] = m[i] + log2_hw(s[i]);
    *(f4*)(d2 + (size_t)n * Tt + t4) = d;
    if (P) {
        float* __restrict__ dst = P + (size_t)n * Cc * Tt + t4;
        #pragma unroll 4
        for (int c = 0; c < Cc; ++c) {
            f4 v = LD4(p + (size_t)c * Tt);
            f4 o;
            #pragma unroll
            for (int i = 0; i < 4; ++i) o[i] = exp2_hw(fmaf(v[i], IL2f, -d[i]));
            *(f4*)(dst + (size_t)c * Tt) = o;
        }
    }
}

// ---------------- Kernel 2: fwd/bwd recurrence, linear domain, per-lane exponent ----
// 16-step groups, 3-slot register ring, lead-2 prefetch (~1000 cy) to cover HBM
// latency. __launch_bounds__(64, 1): 1 wave/EU -> full ~512-VGPR budget so the
// ring stays in registers (R7: at the default 64-VGPR budget MachineSink
// collapsed the pipeline; R8's asm pin forced immediate waitcnt — both wrong).
template<bool PRE>
__global__ __launch_bounds__(64, 1) void ctc_fb_kernel(
    const float* __restrict__ PR, const int* __restrict__ targets,
    const int* __restrict__ tlen, const int* __restrict__ ilen,
    const float* __restrict__ d2, float* __restrict__ wsA, float* __restrict__ wsB)
{
    const int bid = blockIdx.x;
    const int n = bid >> 1;
    const bool bwd = bid & 1;
    const int lane = threadIdx.x;
    const int tl = tlen[n];
    const int Tn = ilen[n];
    const int L = 2 * tl + 1;
    const int mid = Tn >> 1;
    const int s0 = 4 * lane;

    const int j1 = min(2 * lane, Ss - 1);
    const int j3 = min(2 * lane + 1, Ss - 1);
    const int base = n * Ss;
    const int tg1 = targets[base + j1];
    const int tg3 = targets[base + j3];
    const int tg1m = targets[base + max(2 * lane - 1, 0)];
    const int tg3p = targets[base + min(2 * lane + 2, Ss - 1)];

    const float sk1f = ((s0 + 1 >= 3) && (tg1 != tg1m)) ? 1.f : 0.f;
    const float sk3f = (tg3 != tg1) ? 1.f : 0.f;
    const float sk1b = ((s0 + 3 < L) && (tg3 != tg1)) ? 1.f : 0.f;
    const float sk3b = ((s0 + 5 < L) && (tg3p != tg3)) ? 1.f : 0.f;

    const float* __restrict__ rB = PR + (size_t)(n * Cc) * Tt;
    const float* __restrict__ r1 = PR + (size_t)(n * Cc + tg1) * Tt;
    const float* __restrict__ r3 = PR + (size_t)(n * Cc + tg3) * Tt;
    const float* __restrict__ rD = d2 + (size_t)n * Tt;

    float a0, a1, a2, a3;
    int E = 0;

    if (!bwd) {
        float pB0, p10;
        if constexpr (PRE) { pB0 = rB[0]; p10 = r1[0]; }
        else {
            const float dv = rD[0];
            pB0 = exp2_hw(fmaf(rB[0], IL2f, -dv));
            p10 = exp2_hw(fmaf(r1[0], IL2f, -dv));
        }
        a0 = (lane == 0) ? pB0 : 0.f;
        a1 = (lane == 0) ? p10 : 0.f;
        a2 = 0.f; a3 = 0.f;
    } else {
        const int te = Tn - 1;
        float pBe, p1e, p3e;
        if constexpr (PRE) { pBe = rB[te]; p1e = r1[te]; p3e = r3[te]; }
        else {
            const float dv = rD[te];
            pBe = exp2_hw(fmaf(rB[te], IL2f, -dv));
            p1e = exp2_hw(fmaf(r1[te], IL2f, -dv));
            p3e = exp2_hw(fmaf(r3[te], IL2f, -dv));
        }
        const int sl = 2 * tl;
        a0 = (s0 == sl) ? pBe : 0.f;
        a1 = (s0 + 1 == sl - 1) ? p1e : 0.f;
        a2 = (s0 + 2 == sl) ? pBe : 0.f;
        a3 = (s0 + 3 == sl - 1) ? p3e : 0.f;
    }

    f4 bB[3][4], bU[3][4], bW[3][4], bD[3][4];

    #define GETP(arr, sl, k) (arr[sl][(k) >> 2][(k) & 3])

    if (!bwd) {
        const int tB = mid;                      // steps t = 1..tB
        const int gHi = tB >> 4;                 // 16-step groups

        #define ISSUE_F(gg, sl) {                                                   \
            const int gc_ = min((gg), gHi); const int bo_ = gc_ * 16;               \
            bB[sl][0]=LD4(rB+bo_); bB[sl][1]=LD4(rB+bo_+4);                         \
            bB[sl][2]=LD4(rB+bo_+8); bB[sl][3]=LD4(rB+bo_+12);                      \
            bU[sl][0]=LD4(r1+bo_); bU[sl][1]=LD4(r1+bo_+4);                         \
            bU[sl][2]=LD4(r1+bo_+8); bU[sl][3]=LD4(r1+bo_+12);                      \
            bW[sl][0]=LD4(r3+bo_); bW[sl][1]=LD4(r3+bo_+4);                         \
            bW[sl][2]=LD4(r3+bo_+8); bW[sl][3]=LD4(r3+bo_+12);                      \
            if constexpr (!PRE) {                                                   \
                bD[sl][0]=LD4(rD+bo_); bD[sl][1]=LD4(rD+bo_+4);                     \
                bD[sl][2]=LD4(rD+bo_+8); bD[sl][3]=LD4(rD+bo_+12); }               \
        }

        #define BODY_F(gg, us, is) {                                                \
            ISSUE_F((gg) + 2, is);                                                  \
            _Pragma("unroll")                                                       \
            for (int w = 0; w < 2; ++w) {                                           \
                const int Eu = wave_shr1_i(E);                                      \
                const int eb = min(max(127 + (Eu - E), 0), 230);                    \
                const float sc = __int_as_float((unsigned)eb << 23);                \
                const float sk1fs = sk1f * sc;                                      \
                _Pragma("unroll")                                                   \
                for (int kk = 0; kk < 8; ++kk) {                                    \
                    const int k = w * 8 + kk;                                       \
                    const int t = (gg) * 16 + k;                                    \
                    if (t >= 1 && t <= tB) {                                        \
                        float pB, p1, p3;                                           \
                        if constexpr (PRE) {                                        \
                            pB = GETP(bB, us, k); p1 = GETP(bU, us, k);             \
                            p3 = GETP(bW, us, k);                                   \
                        } else {                                                    \
                            const float dv = GETP(bD, us, k);                       \
                            pB = exp2_hw(fmaf(GETP(bB, us, k), IL2f, -dv));         \
                            p1 = exp2_hw(fmaf(GETP(bU, us, k), IL2f, -dv));         \
                            p3 = exp2_hw(fmaf(GETP(bW, us, k), IL2f, -dv));         \
                        }                                                           \
                        const float u3 = wave_shr1(a3);                             \
                        const float n3 = fmaf(a1, sk3f, a3 + a2) * p3;              \
                        const float n2 = (a2 + a1) * pB;                            \
                        const float n1 = fmaf(u3, sk1fs, a1 + a0) * p1;             \
                        const float n0 = fmaf(u3, sc, a0) * pB;                     \
                        a0 = n0; a1 = n1; a2 = n2; a3 = n3;                         \
                    }                                                               \
                }                                                                   \
                const float mx = fmaxf(fmaxf(a0, a1), fmaxf(a2, a3));               \
                const int me = (int)(__float_as_uint(mx) >> 23);                    \
                const float sc2 = __int_as_float((unsigned)(254 - me) << 23);       \
                a0 *= sc2; a1 *= sc2; a2 *= sc2; a3 *= sc2;                         \
                E = (mx > 0.f) ? (E + me - 127) : Eu;                               \
            }                                                                       \
        }

        ISSUE_F(0, 0);
        ISSUE_F(1, 1);
        for (int g = 0; g <= gHi; g += 3) {
            BODY_F(g, 0, 2);
            if (g + 1 <= gHi) BODY_F(g + 1, 1, 0);
            if (g + 2 <= gHi) BODY_F(g + 2, 2, 1);
        }
        #undef BODY_F
        #undef ISSUE_F
    } else {
        const int tB = Tn - 2, tA = mid + 1;     // steps t = tB .. tA (descending)
        const int gHi = tB >> 4, gLo = tA >> 4;

        #define ISSUE_B(gg, sl) {                                                   \
            const int gc_ = max((gg), 0); const int bo_ = gc_ * 16;                 \
            bB[sl][0]=LD4(rB+bo_); bB[sl][1]=LD4(rB+bo_+4);                         \
            bB[sl][2]=LD4(rB+bo_+8); bB[sl][3]=LD4(rB+bo_+12);                      \
            bU[sl][0]=LD4(r1+bo_); bU[sl][1]=LD4(r1+bo_+4);                         \
            bU[sl][2]=LD4(r1+bo_+8); bU[sl][3]=LD4(r1+bo_+12);                      \
            bW[sl][0]=LD4(r3+bo_); bW[sl][1]=LD4(r3+bo_+4);                         \
            bW[sl][2]=LD4(r3+bo_+8); bW[sl][3]=LD4(r3+bo_+12);                      \
            if constexpr (!PRE) {                                                   \
                bD[sl][0]=LD4(rD+bo_); bD[sl][1]=LD4(rD+bo_+4);                     \
                bD[sl][2]=LD4(rD+bo_+8); bD[sl][3]=LD4(rD+bo_+12); }               \
        }

        #define BODY_B(gg, us, is) {                                                \
            ISSUE_B((gg) - 2, is);                                                  \
            _Pragma("unroll")                                                       \
            for (int w = 1; w >= 0; --w) {                                          \
                const int Ed = wave_shl1_i(E);                                      \
                const int eb = min(max(127 + (Ed - E), 0), 230);                    \
                const float sc = __int_as_float((unsigned)eb << 23);                \
                const float sk3bs = sk3b * sc;                                      \
                _Pragma("unroll")                                                   \
                for (int kk = 7; kk >= 0; --kk) {                                   \
                    const int k = w * 8 + kk;                                       \
                    const int t = (gg) * 16 + k;                                    \
                    if (t >= tA && t <= tB) {                                       \
                        float pB, p1, p3;                                           \
                        if constexpr (PRE) {                                        \
                            pB = GETP(bB, us, k); p1 = GETP(bU, us, k);             \
                            p3 = GETP(bW, us, k);                                   \
                        } else {                                                    \
                            const float dv = GETP(bD, us, k);                       \
                            pB = exp2_hw(fmaf(GETP(bB, us, k), IL2f, -dv));         \
                            p1 = exp2_hw(fmaf(GETP(bU, us, k), IL2f, -dv));         \
                            p3 = exp2_hw(fmaf(GETP(bW, us, k), IL2f, -dv));         \
                        }                                                           \
                        const float d0 = wave_shl1(a0);                             \
                        const float d1 = wave_shl1(a1);                             \
                        const float n0 = (a0 + a1) * pB;                            \
                        const float n1 = fmaf(a3, sk1b, a1 + a2) * p1;              \
                        const float n2 = (a2 + a3) * pB;                            \
                        const float n3 = fmaf(d1, sk3bs, fmaf(d0, sc, a3)) * p3;    \
                        a0 = n0; a1 = n1; a2 = n2; a3 = n3;                         \
                    }                                                               \
                }                                                                   \
                const float mx = fmaxf(fmaxf(a0, a1), fmaxf(a2, a3));               \
                const int me = (int)(__float_as_uint(mx) >> 23);                    \
                const float sc2 = __int_as_float((unsigned)(254 - me) << 23);       \
                a0 *= sc2; a1 *= sc2; a2 *= sc2; a3 *= sc2;                         \
                E = (mx > 0.f) ? (E + me - 127) : Ed;                               \
            }                                                                       \
        }

        ISSUE_B(gHi, 0);
        ISSUE_B(gHi - 1, 1);
        for (int g = gHi; g >= gLo; g -= 3) {
            BODY_B(g, 0, 2);
            if (g - 1 >= gLo) BODY_B(g - 1, 1, 0);
            if (g - 2 >= gLo) BODY_B(g - 2, 2, 1);
        }
        #undef BODY_B
        #undef ISSUE_B
    }
    #undef GETP

    // convert to log2 domain for the combine kernel
    float* dst = (bwd ? wsB : wsA) + n * 256;
    const float Ef = (float)E;
    f4 o;
    o[0] = (s0     < L && a0 > 0.f) ? log2_hw(a0) + Ef : NEGV;
    o[1] = (s0 + 1 < L && a1 > 0.f) ? log2_hw(a1) + Ef : NEGV;
    o[2] = (s0 + 2 < L && a2 > 0.f) ? log2_hw(a2) + Ef : NEGV;
    o[3] = (s0 + 3 < L && a3 > 0.f) ? log2_hw(a3) + Ef : NEGV;
    *(f4*)(dst + s0) = o;
}

// ---------------- Kernel 3: splice alpha*beta, lse over states, mean ----------------
__global__ __launch_bounds__(64) void ctc_combine_kernel(
    const float* __restrict__ wsA, const float* __restrict__ wsB,
    const int* __restrict__ targets, const int* __restrict__ tlen,
    float* __restrict__ out)
{
    const int n = blockIdx.x;
    const int lane = threadIdx.x;
    const int tl = tlen[n];
    const int L = 2 * tl + 1;
    float vals[4];
    float vmax = NEGV;
    #pragma unroll
    for (int k = 0; k < 4; ++k) {
        const int s = lane + (k << 6);
        float v = NEGV;
        if (s < L) {
            const float al = wsA[n * 256 + s];
            const float b0 = wsB[n * 256 + s];
            const float b1 = (s + 1 < L) ? wsB[n * 256 + s + 1] : NEGV;
            const bool skip = (s & 1) && (s + 2 < L) &&
                (targets[n * Ss + (s >> 1) + 1] != targets[n * Ss + (s >> 1)]);
            const float b2 = skip ? wsB[n * 256 + s + 2] : NEGV;
            const float m3 = fmaxf(fmaxf(b0, b1), b2);
            const float B = m3 + log2_hw(exp2_hw(b0 - m3) + exp2_hw(b1 - m3) + exp2_hw(b2 - m3));
            v = al + B;
        }
        vals[k] = v;
        vmax = fmaxf(vmax, v);
    }
    #pragma unroll
    for (int o = 32; o; o >>= 1) vmax = fmaxf(vmax, __shfl_xor(vmax, o));
    float ssum = 0.f;
    #pragma unroll
    for (int k = 0; k < 4; ++k) ssum += exp2_hw(vals[k] - vmax);
    #pragma unroll
    for (int o = 32; o; o >>= 1) ssum += __shfl_xor(ssum, o);
    if (lane == 0) {
        const float total2 = vmax + log2_hw(ssum);
        const float loss = -LN2f * total2;
        atomicAdd(out, loss / ((float)tl * (float)Nn));
    }
}

extern "C" void kernel_launch(void* const* d_in, const int* in_sizes, int n_in,
                              void* d_out, int out_size, void* d_ws, size_t ws_size,
                              hipStream_t stream) {
    const float* logits = (const float*)d_in[0];
    const int* targets  = (const int*)d_in[1];
    const int* tlen     = (const int*)d_in[2];
    const int* ilen     = (const int*)d_in[3];
    float* out = (float*)d_out;

    float* wsA = (float*)d_ws;                     // 64*256
    float* wsB = wsA + Nn * 256;                   // 64*256
    float* d2  = wsB + Nn * 256;                   // 64*4000
    float* P   = d2 + (size_t)Nn * Tt;             // 64*64*4000 (if it fits)
    const size_t need = ((size_t)Nn * 256 * 2 + (size_t)Nn * Tt
                         + (size_t)Nn * Cc * Tt) * sizeof(float);
    const bool pre = (ws_size >= need);

    hipMemsetAsync(d_out, 0, sizeof(float), stream);
    ctc_softmax_kernel<<<dim3(4, Nn), 256, 0, stream>>>(logits, d2, pre ? P : nullptr);
    if (pre) {
        ctc_fb_kernel<true><<<Nn * 2, 64, 0, stream>>>(P, targets, tlen, ilen, d2, wsA, wsB);
    } else {
        ctc_fb_kernel<false><<<Nn * 2, 64, 0, stream>>>(logits, targets, tlen, ilen, d2, wsA, wsB);
    }
    ctc_combine_kernel<<<Nn, 64, 0, stream>>>(wsA, wsB, targets, tlen, out);
}